// Round 1
// baseline (625.260 us; speedup 1.0000x reference)
//
#include <hip/hip_runtime.h>
#include <hip/hip_fp16.h>

#define Bb 4
#define Ss 1024
#define HID 1024
#define NH 16
#define NKV 8
#define HD 64

typedef _Float16 f16x8 __attribute__((ext_vector_type(8)));
typedef float f32x4 __attribute__((ext_vector_type(4)));

// ---------------- fp32 -> fp16 conversion ----------------
__global__ __launch_bounds__(256) void f2h_kernel(const float* __restrict__ in,
                                                  _Float16* __restrict__ out, int n) {
  int i = blockIdx.x * 256 + threadIdx.x;
  if (i < n) out[i] = (_Float16)in[i];
}

// ---------------- fp16 MFMA GEMM: C(MxN) = A(MxK) * Bt(NxK)^T ----------------
// 64x64 block tile, 4 waves, 16x16x32 MFMA.
// A-frag: row = lane&15, k = (lane>>4)*8 + e (8 contiguous fp16 -> ds_read_b128)
// C/D   : col = lane&15, row = (lane>>4)*4 + reg   [m89/m91-verified]
__global__ __launch_bounds__(256) void gemm_bt_f16(
    const _Float16* __restrict__ A, const _Float16* __restrict__ Bt,
    float* __restrict__ C, int M, int N, int K) {
  __shared__ _Float16 As[4][64][8];  // [k-chunk][row][e]
  __shared__ _Float16 Bs[4][64][8];  // [k-chunk][col][e]
  const int tid  = threadIdx.x;
  const int wave = tid >> 6;
  const int lane = tid & 63;
  const int lr = lane & 15;
  const int lk = lane >> 4;
  const int bm = blockIdx.x * 64;
  const int bn = blockIdx.y * 64;
  const int sr  = tid >> 2;       // staging row 0..63
  const int skc = tid & 3;        // staging k-chunk 0..3
  const _Float16* Ap = A  + (size_t)(bm + sr) * K + skc * 8;
  const _Float16* Bp = Bt + (size_t)(bn + sr) * K + skc * 8;
  f32x4 acc[4];
  const f32x4 zero = {0.f, 0.f, 0.f, 0.f};
#pragma unroll
  for (int n = 0; n < 4; ++n) acc[n] = zero;

  for (int k0 = 0; k0 < K; k0 += 32) {
    *(f16x8*)(&As[skc][sr][0]) = *(const f16x8*)(Ap + k0);
    *(f16x8*)(&Bs[skc][sr][0]) = *(const f16x8*)(Bp + k0);
    __syncthreads();
    f16x8 af = *(const f16x8*)(&As[lk][wave * 16 + lr][0]);
#pragma unroll
    for (int n = 0; n < 4; ++n) {
      f16x8 bf = *(const f16x8*)(&Bs[lk][n * 16 + lr][0]);
      acc[n] = __builtin_amdgcn_mfma_f32_16x16x32_f16(af, bf, acc[n], 0, 0, 0);
    }
    __syncthreads();
  }
  const int row0 = bm + wave * 16 + lk * 4;
#pragma unroll
  for (int n = 0; n < 4; ++n) {
    const int c = bn + n * 16 + lr;
#pragma unroll
    for (int j = 0; j < 4; ++j)
      C[(size_t)(row0 + j) * N + c] = acc[n][j];
  }
}

// ---------------- RMSNorm(HD=64) + RoPE, in place, one wave per (row, head) --
__global__ __launch_bounds__(256) void rmsrope_kernel(
    float* __restrict__ buf, const float* __restrict__ w,
    const float* __restrict__ cosd, const float* __restrict__ sind, int heads) {
  const int wid  = blockIdx.x * 4 + (threadIdx.x >> 6);
  const int lane = threadIdx.x & 63;
  const int h   = wid % heads;
  const int row = wid / heads;  // b*S + s
  const size_t idx = (size_t)row * (heads * HD) + h * HD + lane;
  float x = buf[idx];
  float ss = x * x;
#pragma unroll
  for (int o = 32; o > 0; o >>= 1) ss += __shfl_xor(ss, o);
  float y = x * rsqrtf(ss * (1.0f / 64.0f) + 1e-6f) * w[lane];
  float yr = __shfl_xor(y, 32);
  float rot = (lane < 32) ? -yr : yr;
  const int ci = row * HD + lane;
  buf[idx] = y * cosd[ci] + rot * sind[ci];
}

// ---------------- causal GQA attention, block = (b, h, 64 q-rows) -----------
// Pass 1: scores (scaled+masked) -> raw into attn area, online m,l.
// Pass 2: w = exp(s-m)/l -> attn area (final), ctx += w @ V -> fp16 ctx buf.
__global__ __launch_bounds__(256) void attn_kernel(
    const float* __restrict__ qb, const float* __restrict__ kb,
    const float* __restrict__ vb, float* __restrict__ attn,
    _Float16* __restrict__ ctxh) {
  __shared__ float Qs[64][68], Ks[64][68], Vs[64][68], Wt[64][68];
  __shared__ float mrow[64], lirow[64];
  const int qt = blockIdx.x, h = blockIdx.y, b = blockIdx.z;
  const int kvh = h >> 1;  // groups = NH/NKV = 2
  const int tid = threadIdx.x;
  const int ty = tid >> 4, tx = tid & 15;
  const int q0 = qt * 64;
  float* attn_bh = attn + (size_t)(b * NH + h) * Ss * Ss;

  for (int idx = tid; idx < 64 * 16; idx += 256) {
    int r = idx >> 4, c4 = (idx & 15) * 4;
    *(float4*)&Qs[r][c4] =
        *(const float4*)&qb[(size_t)(b * Ss + q0 + r) * HID + h * HD + c4];
  }

  float m[4], l[4];
#pragma unroll
  for (int i = 0; i < 4; ++i) { m[i] = -3.0e38f; l[i] = 0.f; }

  // ---- pass 1 ----
  for (int t = 0; t <= qt; ++t) {
    __syncthreads();
    for (int idx = tid; idx < 64 * 16; idx += 256) {
      int r = idx >> 4, c4 = (idx & 15) * 4;
      *(float4*)&Ks[r][c4] =
          *(const float4*)&kb[(size_t)(b * Ss + t * 64 + r) * (NKV * HD) + kvh * HD + c4];
    }
    __syncthreads();
    float s[4][4];
#pragma unroll
    for (int i = 0; i < 4; ++i)
#pragma unroll
      for (int j = 0; j < 4; ++j) s[i][j] = 0.f;
    for (int d = 0; d < 64; ++d) {
      float qv[4], kv[4];
#pragma unroll
      for (int i = 0; i < 4; ++i) qv[i] = Qs[ty * 4 + i][d];
#pragma unroll
      for (int j = 0; j < 4; ++j) kv[j] = Ks[j * 16 + tx][d];
#pragma unroll
      for (int i = 0; i < 4; ++i)
#pragma unroll
        for (int j = 0; j < 4; ++j) s[i][j] += qv[i] * kv[j];
    }
#pragma unroll
    for (int i = 0; i < 4; ++i) {
      const int gr = q0 + ty * 4 + i;
#pragma unroll
      for (int j = 0; j < 4; ++j) {
        const int gc = t * 64 + j * 16 + tx;
        s[i][j] = s[i][j] * 0.125f + (gc <= gr ? 0.f : -1.0e9f);
      }
    }
#pragma unroll
    for (int i = 0; i < 4; ++i) {
      float pm = fmaxf(fmaxf(s[i][0], s[i][1]), fmaxf(s[i][2], s[i][3]));
#pragma unroll
      for (int o = 1; o < 16; o <<= 1) pm = fmaxf(pm, __shfl_xor(pm, o));
      const float mn = fmaxf(m[i], pm);
      float ps = 0.f;
#pragma unroll
      for (int j = 0; j < 4; ++j) ps += __expf(s[i][j] - mn);
#pragma unroll
      for (int o = 1; o < 16; o <<= 1) ps += __shfl_xor(ps, o);
      l[i] = l[i] * __expf(m[i] - mn) + ps;
      m[i] = mn;
    }
#pragma unroll
    for (int i = 0; i < 4; ++i)
#pragma unroll
      for (int j = 0; j < 4; ++j) Wt[ty * 4 + i][j * 16 + tx] = s[i][j];
    __syncthreads();
    for (int idx = tid; idx < 64 * 16; idx += 256) {
      int r = idx >> 4, c4 = (idx & 15) * 4;
      *(float4*)&attn_bh[(size_t)(q0 + r) * Ss + t * 64 + c4] = *(float4*)&Wt[r][c4];
    }
  }
  if (tx == 0) {
#pragma unroll
    for (int i = 0; i < 4; ++i) {
      mrow[ty * 4 + i] = m[i];
      lirow[ty * 4 + i] = 1.0f / l[i];
    }
  }
  __threadfence();
  __syncthreads();

  // ---- pass 2 ----
  float cacc[4][4];
#pragma unroll
  for (int i = 0; i < 4; ++i)
#pragma unroll
    for (int j = 0; j < 4; ++j) cacc[i][j] = 0.f;

  for (int t = 0; t <= qt; ++t) {
    for (int idx = tid; idx < 64 * 16; idx += 256) {
      int r = idx >> 4, c4 = (idx & 15) * 4;
      *(float4*)&Vs[r][c4] =
          *(const float4*)&vb[(size_t)(b * Ss + t * 64 + r) * (NKV * HD) + kvh * HD + c4];
    }
    for (int idx = tid; idx < 64 * 16; idx += 256) {
      int r = idx >> 4, c4 = (idx & 15) * 4;
      float4 sv = *(const float4*)&attn_bh[(size_t)(q0 + r) * Ss + t * 64 + c4];
      const float mm = mrow[r], li = lirow[r];
      float4 wv;
      wv.x = __expf(sv.x - mm) * li;
      wv.y = __expf(sv.y - mm) * li;
      wv.z = __expf(sv.z - mm) * li;
      wv.w = __expf(sv.w - mm) * li;
      *(float4*)&attn_bh[(size_t)(q0 + r) * Ss + t * 64 + c4] = wv;
      *(float4*)&Wt[r][c4] = wv;
    }
    __syncthreads();
    for (int jj = 0; jj < 64; ++jj) {
      float wv[4], vv[4];
#pragma unroll
      for (int i = 0; i < 4; ++i) wv[i] = Wt[ty * 4 + i][jj];
#pragma unroll
      for (int dd = 0; dd < 4; ++dd) vv[dd] = Vs[jj][tx * 4 + dd];
#pragma unroll
      for (int i = 0; i < 4; ++i)
#pragma unroll
        for (int dd = 0; dd < 4; ++dd) cacc[i][dd] += wv[i] * vv[dd];
    }
    __syncthreads();
  }
  // zero fully-masked tiles (output must be fully written; harness poisons)
  for (int t = qt + 1; t < 16; ++t) {
    const float4 z = make_float4(0.f, 0.f, 0.f, 0.f);
    for (int idx = tid; idx < 64 * 16; idx += 256) {
      int r = idx >> 4, c4 = (idx & 15) * 4;
      *(float4*)&attn_bh[(size_t)(q0 + r) * Ss + t * 64 + c4] = z;
    }
  }
#pragma unroll
  for (int i = 0; i < 4; ++i)
#pragma unroll
    for (int dd = 0; dd < 4; ++dd)
      ctxh[(size_t)(b * Ss + q0 + ty * 4 + i) * HID + h * HD + tx * 4 + dd] =
          (_Float16)cacc[i][dd];
}

// ---------------- launch ----------------
extern "C" void kernel_launch(void* const* d_in, const int* in_sizes, int n_in,
                              void* d_out, int out_size, void* d_ws, size_t ws_size,
                              hipStream_t stream) {
  const float* hs   = (const float*)d_in[0];
  const float* cosb = (const float*)d_in[1];
  const float* sinb = (const float*)d_in[2];
  // d_in[3] attention_mask: causal, reproduced analytically
  const float* Wq = (const float*)d_in[4];
  const float* Wk = (const float*)d_in[5];
  const float* Wv = (const float*)d_in[6];
  const float* Wo = (const float*)d_in[7];
  const float* qw = (const float*)d_in[8];
  const float* kw = (const float*)d_in[9];

  char* ws = (char*)d_ws;
  _Float16* Xh   = (_Float16*)(ws);             // 4096x1024 fp16   (8 MB)
  _Float16* Wqh  = (_Float16*)(ws + 8388608);   // 1024x1024        (2 MB)
  _Float16* Wkh  = (_Float16*)(ws + 10485760);  // 512x1024         (1 MB)
  _Float16* Wvh  = (_Float16*)(ws + 11534336);  // 512x1024         (1 MB)
  _Float16* Woh  = (_Float16*)(ws + 12582912);  // 1024x1024        (2 MB)
  float*    qbuf = (float*)(ws + 14680064);     // 4096x1024 f32   (16 MB)
  float*    kbuf = (float*)(ws + 31457280);     // 4096x512  f32    (8 MB)
  float*    vbuf = (float*)(ws + 39845888);     // 4096x512  f32    (8 MB)
  _Float16* ctxh = (_Float16*)(ws + 48234496);  // 4096x1024 fp16   (8 MB)

  float* out  = (float*)d_out;
  float* attn = out + (size_t)Bb * Ss * HID;  // second output region

  f2h_kernel<<<4194304 / 256, 256, 0, stream>>>(hs, Xh, 4194304);
  f2h_kernel<<<1048576 / 256, 256, 0, stream>>>(Wq, Wqh, 1048576);
  f2h_kernel<<< 524288 / 256, 256, 0, stream>>>(Wk, Wkh, 524288);
  f2h_kernel<<< 524288 / 256, 256, 0, stream>>>(Wv, Wvh, 524288);
  f2h_kernel<<<1048576 / 256, 256, 0, stream>>>(Wo, Woh, 1048576);

  gemm_bt_f16<<<dim3(64, 16), 256, 0, stream>>>(Xh, Wqh, qbuf, 4096, 1024, 1024);
  gemm_bt_f16<<<dim3(64, 8),  256, 0, stream>>>(Xh, Wkh, kbuf, 4096, 512, 1024);
  gemm_bt_f16<<<dim3(64, 8),  256, 0, stream>>>(Xh, Wvh, vbuf, 4096, 512, 1024);

  rmsrope_kernel<<<(4096 * 16) / 4, 256, 0, stream>>>(qbuf, qw, cosb, sinb, 16);
  rmsrope_kernel<<<(4096 * 8) / 4, 256, 0, stream>>>(kbuf, kw, cosb, sinb, 8);

  attn_kernel<<<dim3(16, 16, 4), 256, 0, stream>>>(qbuf, kbuf, vbuf, attn, ctxh);

  gemm_bt_f16<<<dim3(64, 16), 256, 0, stream>>>(ctxh, Woh, out, 4096, 1024, 1024);
}

// Round 2
// 221.690 us; speedup vs baseline: 2.8204x; 2.8204x over previous
//
#include <hip/hip_runtime.h>
#include <hip/hip_fp16.h>

#define Bb 4
#define Ss 1024
#define HID 1024
#define NH 16
#define NKV 8
#define HD 64

typedef _Float16 f16x8 __attribute__((ext_vector_type(8)));
typedef float f32x4 __attribute__((ext_vector_type(4)));

// ---------------- fp32 -> fp16 conversion ----------------
__global__ __launch_bounds__(256) void f2h_kernel(const float* __restrict__ in,
                                                  _Float16* __restrict__ out, int n) {
  int i = blockIdx.x * 256 + threadIdx.x;
  if (i < n) out[i] = (_Float16)in[i];
}

// ---------------- fp16 MFMA GEMM: C(MxN) = A(MxK) * Bt(NxK)^T ----------------
// 64x64 block tile, 4 waves, 16x16x32 MFMA.
// A-frag: row = lane&15, k = (lane>>4)*8 + e  (8 contiguous fp16, ds_read_b128)
// C/D   : col = lane&15, row = (lane>>4)*4 + reg   [m89/m91-verified]
// EPI: 0 = fp32 C store; 1 = fused RMSNorm+RoPE, fp16 store (N-tile == one head);
//      2 = plain fp16 store.
template <int EPI>
__global__ __launch_bounds__(256) void gemm_bt(
    const _Float16* __restrict__ A, const _Float16* __restrict__ Bt,
    float* __restrict__ C, _Float16* __restrict__ Ch,
    const float* __restrict__ nw, const float* __restrict__ cosd,
    const float* __restrict__ sind, int M, int N, int K) {
  __shared__ _Float16 As[4][64][8];
  __shared__ _Float16 Bs[4][64][8];
  const int tid  = threadIdx.x;
  const int wave = tid >> 6;
  const int lane = tid & 63;
  const int lr = lane & 15;
  const int lk = lane >> 4;
  const int bm = blockIdx.x * 64;
  const int bn = blockIdx.y * 64;
  const int sr  = tid >> 2;
  const int skc = tid & 3;
  const _Float16* Ap = A  + (size_t)(bm + sr) * K + skc * 8;
  const _Float16* Bp = Bt + (size_t)(bn + sr) * K + skc * 8;
  f32x4 acc[4];
  const f32x4 zero = {0.f, 0.f, 0.f, 0.f};
#pragma unroll
  for (int n = 0; n < 4; ++n) acc[n] = zero;

  for (int k0 = 0; k0 < K; k0 += 32) {
    *(f16x8*)(&As[skc][sr][0]) = *(const f16x8*)(Ap + k0);
    *(f16x8*)(&Bs[skc][sr][0]) = *(const f16x8*)(Bp + k0);
    __syncthreads();
    f16x8 af = *(const f16x8*)(&As[lk][wave * 16 + lr][0]);
#pragma unroll
    for (int n = 0; n < 4; ++n) {
      f16x8 bf = *(const f16x8*)(&Bs[lk][n * 16 + lr][0]);
      acc[n] = __builtin_amdgcn_mfma_f32_16x16x32_f16(af, bf, acc[n], 0, 0, 0);
    }
    __syncthreads();
  }
  const int row0 = bm + wave * 16 + lk * 4;
  if (EPI == 0) {
#pragma unroll
    for (int n = 0; n < 4; ++n) {
      const int c = bn + n * 16 + lr;
#pragma unroll
      for (int j = 0; j < 4; ++j)
        C[(size_t)(row0 + j) * N + c] = acc[n][j];
    }
  } else if (EPI == 2) {
#pragma unroll
    for (int n = 0; n < 4; ++n) {
      const int c = bn + n * 16 + lr;
#pragma unroll
      for (int j = 0; j < 4; ++j)
        Ch[(size_t)(row0 + j) * N + c] = (_Float16)acc[n][j];
    }
  } else {
    // fused RMSNorm(64) + RoPE. Row's 64 head-dims live in 16 lanes x 4 regs.
    float rs[4];
#pragma unroll
    for (int j = 0; j < 4; ++j) {
      float ss = 0.f;
#pragma unroll
      for (int n = 0; n < 4; ++n) ss += acc[n][j] * acc[n][j];
#pragma unroll
      for (int o = 1; o < 16; o <<= 1) ss += __shfl_xor(ss, o);
      rs[j] = rsqrtf(ss * (1.0f / 64.0f) + 1e-6f);
    }
#pragma unroll
    for (int j = 0; j < 4; ++j) {
      float y[4];
#pragma unroll
      for (int n = 0; n < 4; ++n) y[n] = acc[n][j] * rs[j] * nw[n * 16 + lr];
      const size_t rb = (size_t)(row0 + j) * HD;
#pragma unroll
      for (int n = 0; n < 4; ++n) {
        const int d = n * 16 + lr;
        const float rot = (n < 2) ? -y[n + 2] : y[n - 2];
        const float o = y[n] * cosd[rb + d] + rot * sind[rb + d];
        Ch[(size_t)(row0 + j) * N + bn + d] = (_Float16)o;
      }
    }
  }
}

// ---------------- V transpose: vh [b*S][NKV*HD] -> vT [(b*NKV+kv)*64+d][S] ----
__global__ __launch_bounds__(256) void vtrans_kernel(const _Float16* __restrict__ vh,
                                                     _Float16* __restrict__ vT) {
  __shared__ __align__(16) _Float16 T[64][72];
  const int s0 = blockIdx.x * 64;
  const int kv = blockIdx.y;
  const int b  = blockIdx.z;
  const int tid = threadIdx.x;
  for (int idx = tid; idx < 512; idx += 256) {
    int r = idx >> 3, c = idx & 7;
    *(f16x8*)&T[r][c * 8] =
        *(const f16x8*)&vh[(size_t)(b * Ss + s0 + r) * (NKV * HD) + kv * HD + c * 8];
  }
  __syncthreads();
  for (int idx = tid; idx < 512; idx += 256) {
    int d = idx >> 3, c = idx & 7;
    f16x8 v;
#pragma unroll
    for (int e = 0; e < 8; ++e) v[e] = T[c * 8 + e][d];
    *(f16x8*)&vT[(size_t)((b * NKV + kv) * HD + d) * Ss + s0 + c * 8] = v;
  }
}

// ---------------- MFMA flash attention, two-pass, weights written once -------
// Block = (qt, h, b): 64 q-rows, 4 waves (wave w owns q rows w*16..w*16+15).
// Pass A: QK^T MFMA -> online (m,l) per row (kept in registers).
// Pass B: QK^T again, w = exp(s-m)/l -> Wh fp16 (LDS) -> HBM fp32 + PV MFMA.
__global__ __launch_bounds__(256, 4) void attn_mfma_kernel(
    const _Float16* __restrict__ qh, const _Float16* __restrict__ kh,
    const _Float16* __restrict__ vT, float* __restrict__ attn,
    _Float16* __restrict__ ctxh) {
  __shared__ __align__(16) _Float16 QV[64][72];  // Q tile, then V^T tile
  __shared__ __align__(16) _Float16 Ks[64][72];
  __shared__ __align__(16) _Float16 Wh[64][72];
  const int qt = blockIdx.x, h = blockIdx.y, b = blockIdx.z;
  const int kvh = h >> 1;  // groups = NH/NKV = 2
  const int tid = threadIdx.x;
  const int wave = tid >> 6, lane = tid & 63;
  const int lr = lane & 15, lk = lane >> 4;
  const int q0 = qt * 64;
  float* attn_bh = attn + (size_t)(b * NH + h) * Ss * Ss;

  // stage Q tile, cache A-frags in registers
  for (int idx = tid; idx < 512; idx += 256) {
    int r = idx >> 3, c = idx & 7;
    *(f16x8*)&QV[r][c * 8] =
        *(const f16x8*)&qh[(size_t)(b * Ss + q0 + r) * (NH * HD) + h * HD + c * 8];
  }
  __syncthreads();
  f16x8 aq[2];
  aq[0] = *(const f16x8*)&QV[wave * 16 + lr][lk * 8];
  aq[1] = *(const f16x8*)&QV[wave * 16 + lr][32 + lk * 8];

  float m[4], l[4];
#pragma unroll
  for (int j = 0; j < 4; ++j) { m[j] = -3.0e38f; l[j] = 0.f; }

  // ---- pass A: online m,l ----
  for (int t = 0; t <= qt; ++t) {
    __syncthreads();
    for (int idx = tid; idx < 512; idx += 256) {
      int r = idx >> 3, c = idx & 7;
      *(f16x8*)&Ks[r][c * 8] =
          *(const f16x8*)&kh[(size_t)(b * Ss + t * 64 + r) * (NKV * HD) + kvh * HD + c * 8];
    }
    __syncthreads();
    f32x4 acc[4];
#pragma unroll
    for (int n = 0; n < 4; ++n) acc[n] = {0.f, 0.f, 0.f, 0.f};
#pragma unroll
    for (int kc = 0; kc < 2; ++kc) {
#pragma unroll
      for (int n = 0; n < 4; ++n) {
        f16x8 bf = *(const f16x8*)&Ks[n * 16 + lr][kc * 32 + lk * 8];
        acc[n] = __builtin_amdgcn_mfma_f32_16x16x32_f16(aq[kc], bf, acc[n], 0, 0, 0);
      }
    }
    const bool diag = (t == qt);
#pragma unroll
    for (int j = 0; j < 4; ++j) {
      const int gr = q0 + wave * 16 + lk * 4 + j;
      float s[4];
#pragma unroll
      for (int n = 0; n < 4; ++n) {
        s[n] = acc[n][j] * 0.125f;
        if (diag && (t * 64 + n * 16 + lr > gr)) s[n] = -1.0e9f;
      }
      float pm = fmaxf(fmaxf(s[0], s[1]), fmaxf(s[2], s[3]));
#pragma unroll
      for (int o = 1; o < 16; o <<= 1) pm = fmaxf(pm, __shfl_xor(pm, o));
      const float mn = fmaxf(m[j], pm);
      float ps = 0.f;
#pragma unroll
      for (int n = 0; n < 4; ++n) ps += __expf(s[n] - mn);
#pragma unroll
      for (int o = 1; o < 16; o <<= 1) ps += __shfl_xor(ps, o);
      l[j] = l[j] * __expf(m[j] - mn) + ps;
      m[j] = mn;
    }
  }
  float linv[4];
#pragma unroll
  for (int j = 0; j < 4; ++j) linv[j] = 1.0f / l[j];

  // ---- pass B: weights + PV ----
  f32x4 acc2[4];
#pragma unroll
  for (int n = 0; n < 4; ++n) acc2[n] = {0.f, 0.f, 0.f, 0.f};

  for (int t = 0; t <= qt; ++t) {
    __syncthreads();  // previous tile's LDS reads done
    for (int idx = tid; idx < 512; idx += 256) {
      int r = idx >> 3, c = idx & 7;
      *(f16x8*)&Ks[r][c * 8] =
          *(const f16x8*)&kh[(size_t)(b * Ss + t * 64 + r) * (NKV * HD) + kvh * HD + c * 8];
      *(f16x8*)&QV[r][c * 8] =
          *(const f16x8*)&vT[(size_t)((b * NKV + kvh) * HD + r) * Ss + t * 64 + c * 8];
    }
    __syncthreads();
    f32x4 acc[4];
#pragma unroll
    for (int n = 0; n < 4; ++n) acc[n] = {0.f, 0.f, 0.f, 0.f};
#pragma unroll
    for (int kc = 0; kc < 2; ++kc) {
#pragma unroll
      for (int n = 0; n < 4; ++n) {
        f16x8 bf = *(const f16x8*)&Ks[n * 16 + lr][kc * 32 + lk * 8];
        acc[n] = __builtin_amdgcn_mfma_f32_16x16x32_f16(aq[kc], bf, acc[n], 0, 0, 0);
      }
    }
    const bool diag = (t == qt);
#pragma unroll
    for (int j = 0; j < 4; ++j) {
      const int gr = q0 + wave * 16 + lk * 4 + j;
#pragma unroll
      for (int n = 0; n < 4; ++n) {
        float s = acc[n][j] * 0.125f;
        if (diag && (t * 64 + n * 16 + lr > gr)) s = -1.0e9f;
        const float w = __expf(s - m[j]) * linv[j];
        Wh[wave * 16 + lk * 4 + j][n * 16 + lr] = (_Float16)w;
      }
    }
    __syncthreads();  // Wh complete for all waves
    // PV MFMA: A = Wh (own q rows), B = V^T tile
#pragma unroll
    for (int kc = 0; kc < 2; ++kc) {
      f16x8 aw = *(const f16x8*)&Wh[wave * 16 + lr][kc * 32 + lk * 8];
#pragma unroll
      for (int n = 0; n < 4; ++n) {
        f16x8 bv = *(const f16x8*)&QV[n * 16 + lr][kc * 32 + lk * 8];
        acc2[n] = __builtin_amdgcn_mfma_f32_16x16x32_f16(aw, bv, acc2[n], 0, 0, 0);
      }
    }
    // weights -> HBM (fp32), coalesced from Wh
    for (int idx = tid; idx < 512; idx += 256) {
      int r = idx >> 3, c = idx & 7;
      f16x8 wv = *(const f16x8*)&Wh[r][c * 8];
      float4 lo = make_float4(wv[0], wv[1], wv[2], wv[3]);
      float4 hi = make_float4(wv[4], wv[5], wv[6], wv[7]);
      float* p = &attn_bh[(size_t)(q0 + r) * Ss + t * 64 + c * 8];
      *(float4*)p = lo;
      *(float4*)(p + 4) = hi;
    }
  }

  // zero the fully-masked tiles (output must be fully written)
  const float4 z4 = make_float4(0.f, 0.f, 0.f, 0.f);
  for (int t = qt + 1; t < 16; ++t)
    for (int idx = tid; idx < 1024; idx += 256) {
      int r = idx >> 4, c4 = (idx & 15) * 4;
      *(float4*)&attn_bh[(size_t)(q0 + r) * Ss + t * 64 + c4] = z4;
    }

  // ctx -> LDS (reuse Wh) -> coalesced fp16 store
  __syncthreads();
#pragma unroll
  for (int n = 0; n < 4; ++n)
#pragma unroll
    for (int j = 0; j < 4; ++j)
      Wh[wave * 16 + lk * 4 + j][n * 16 + lr] = (_Float16)acc2[n][j];
  __syncthreads();
  for (int idx = tid; idx < 512; idx += 256) {
    int r = idx >> 3, c = idx & 7;
    *(f16x8*)&ctxh[(size_t)(b * Ss + q0 + r) * (NH * HD) + h * HD + c * 8] =
        *(const f16x8*)&Wh[r][c * 8];
  }
}

// ---------------- launch ----------------
extern "C" void kernel_launch(void* const* d_in, const int* in_sizes, int n_in,
                              void* d_out, int out_size, void* d_ws, size_t ws_size,
                              hipStream_t stream) {
  const float* hs   = (const float*)d_in[0];
  const float* cosb = (const float*)d_in[1];
  const float* sinb = (const float*)d_in[2];
  // d_in[3] attention_mask: causal, reproduced analytically
  const float* Wq = (const float*)d_in[4];
  const float* Wk = (const float*)d_in[5];
  const float* Wv = (const float*)d_in[6];
  const float* Wo = (const float*)d_in[7];
  const float* qw = (const float*)d_in[8];
  const float* kw = (const float*)d_in[9];

  char* ws = (char*)d_ws;
  _Float16* Xh   = (_Float16*)(ws);             // 4096x1024 fp16  (8 MB)
  _Float16* Wqh  = (_Float16*)(ws + 8388608);   // 1024x1024       (2 MB)
  _Float16* Wkh  = (_Float16*)(ws + 10485760);  // 512x1024        (1 MB)
  _Float16* Wvh  = (_Float16*)(ws + 11534336);  // 512x1024        (1 MB)
  _Float16* Woh  = (_Float16*)(ws + 12582912);  // 1024x1024       (2 MB)
  _Float16* qh   = (_Float16*)(ws + 14680064);  // 4096x1024 fp16  (8 MB)
  _Float16* kh   = (_Float16*)(ws + 23068672);  // 4096x512  fp16  (4 MB)
  _Float16* vh   = (_Float16*)(ws + 27262976);  // 4096x512  fp16  (4 MB)
  _Float16* vT   = (_Float16*)(ws + 31457280);  // 512x... ^T      (4 MB)
  _Float16* ctxh = (_Float16*)(ws + 35651584);  // 4096x1024 fp16  (8 MB)

  float* out  = (float*)d_out;
  float* attn = out + (size_t)Bb * Ss * HID;

  f2h_kernel<<<4194304 / 256, 256, 0, stream>>>(hs, Xh, 4194304);
  f2h_kernel<<<1048576 / 256, 256, 0, stream>>>(Wq, Wqh, 1048576);
  f2h_kernel<<< 524288 / 256, 256, 0, stream>>>(Wk, Wkh, 524288);
  f2h_kernel<<< 524288 / 256, 256, 0, stream>>>(Wv, Wvh, 524288);
  f2h_kernel<<<1048576 / 256, 256, 0, stream>>>(Wo, Woh, 1048576);

  // Q/K with fused RMSNorm+RoPE (fp16 out), V plain fp16 out
  gemm_bt<1><<<dim3(64, 16), 256, 0, stream>>>(Xh, Wqh, nullptr, qh, qw, cosb, sinb,
                                               4096, 1024, 1024);
  gemm_bt<1><<<dim3(64, 8),  256, 0, stream>>>(Xh, Wkh, nullptr, kh, kw, cosb, sinb,
                                               4096, 512, 1024);
  gemm_bt<2><<<dim3(64, 8),  256, 0, stream>>>(Xh, Wvh, nullptr, vh, nullptr, nullptr,
                                               nullptr, 4096, 512, 1024);

  vtrans_kernel<<<dim3(16, 8, 4), 256, 0, stream>>>(vh, vT);

  attn_mfma_kernel<<<dim3(16, 16, 4), 256, 0, stream>>>(qh, kh, vT, attn, ctxh);

  gemm_bt<0><<<dim3(64, 16), 256, 0, stream>>>(ctxh, Woh, out, nullptr, nullptr,
                                               nullptr, nullptr, 4096, 1024, 1024);
}